// Round 3
// baseline (674.870 us; speedup 1.0000x reference)
//
#include <hip/hip_runtime.h>
#include <math.h>

#define V 50000
#define E 300
#define H 2048
#define L 512
#define EH 2348  // E+H

// ---------------- kernel 1: fused front-end, 1280 blocks
// blocks 0..511   : attention scores row = bx (blocks 0..7 also zero attnap)
// blocks 512..1279: gh = h0 @ W_hh.T + b_hh  (depends only on inputs -> overlap)
__global__ void k_front(const int* __restrict__ token, const float* __restrict__ h0,
                        const float* __restrict__ emb, const float* __restrict__ attn_W,
                        const float* __restrict__ attn_b, const float* __restrict__ W_hh,
                        const float* __restrict__ b_hh, float* __restrict__ scores,
                        float* __restrict__ attnap, float* __restrict__ gh) {
    int bx = blockIdx.x;
    int tid = threadIdx.x;
    if (bx < 512) {
        if (bx < 8) attnap[bx * 256 + tid] = 0.f;   // 8*256 == H
        const float* erow = emb + (size_t)token[0] * E;
        const float* wrow = attn_W + (size_t)bx * EH;
        float acc = 0.f;
        for (int j = tid; j < EH; j += 256) {
            float c = (j < E) ? erow[j] : h0[j - E];
            acc += c * wrow[j];
        }
        __shared__ float red[256];
        red[tid] = acc; __syncthreads();
        for (int s = 128; s > 0; s >>= 1) {
            if (tid < s) red[tid] += red[tid + s];
            __syncthreads();
        }
        if (tid == 0) scores[bx] = red[0] + attn_b[bx];
    } else {
        int lane = tid & 63;
        int w = (bx - 512) * 4 + (tid >> 6);        // wave id in [0, 3072)
        const float4* h4 = (const float4*)h0;
        float4 hr[8];
        #pragma unroll
        for (int i = 0; i < 8; i++) hr[i] = h4[i * 64 + lane];
        int r = w * 2;                               // rows r, r+1 of 6144
        const float4* w0 = (const float4*)(W_hh + (size_t)r * H);
        const float4* w1 = (const float4*)(W_hh + (size_t)(r + 1) * H);
        float a0 = 0.f, a1 = 0.f;
        #pragma unroll
        for (int i = 0; i < 8; i++) {
            float4 p = w0[i * 64 + lane];
            float4 q = w1[i * 64 + lane];
            a0 += hr[i].x * p.x + hr[i].y * p.y + hr[i].z * p.z + hr[i].w * p.w;
            a1 += hr[i].x * q.x + hr[i].y * q.y + hr[i].z * q.z + hr[i].w * q.w;
        }
        #pragma unroll
        for (int off = 32; off > 0; off >>= 1) {
            a0 += __shfl_xor(a0, off, 64);
            a1 += __shfl_xor(a1, off, 64);
        }
        if (lane == 0) {
            gh[r]     = a0 + b_hh[r];
            gh[r + 1] = a1 + b_hh[r + 1];
        }
    }
}

// ---------------- kernel 2: fused softmax + attn_apply (64 blocks)
__global__ void k_smax_apply(const float* __restrict__ scores, const float* __restrict__ enc,
                             float* __restrict__ attnap, float* __restrict__ out_attnw) {
    int tid = threadIdx.x;
    int hgroup = blockIdx.x & 7;
    int lchunk = blockIdx.x >> 3;
    __shared__ float e[L];
    __shared__ float red[256];
    float v0 = scores[tid], v1 = scores[tid + 256];
    red[tid] = fmaxf(v0, v1); __syncthreads();
    for (int s = 128; s > 0; s >>= 1) { if (tid < s) red[tid] = fmaxf(red[tid], red[tid + s]); __syncthreads(); }
    float m = red[0]; __syncthreads();
    float e0 = expf(v0 - m), e1 = expf(v1 - m);
    e[tid] = e0; e[tid + 256] = e1;
    red[tid] = e0 + e1; __syncthreads();
    for (int s = 128; s > 0; s >>= 1) { if (tid < s) red[tid] += red[tid + s]; __syncthreads(); }
    float inv = 1.f / red[0];

    int hbase = hgroup * 256;
    int l0 = lchunk * 64;
    float acc = 0.f;
    #pragma unroll 8
    for (int l = 0; l < 64; ++l)
        acc += e[l0 + l] * enc[(size_t)(l0 + l) * H + hbase + tid];
    atomicAdd(&attnap[hbase + tid], acc * inv);

    if (blockIdx.x == 0) {
        out_attnw[tid]       = e[tid] * inv;
        out_attnw[tid + 256] = e[tid + 256] * inv;
    }
}

// ---------------- kernel 3: x = relu(cat(emb_row, attn_applied) @ comb_W.T + comb_b)
__global__ void k_combine(const int* __restrict__ token, const float* __restrict__ emb,
                          const float* __restrict__ attn_applied, const float* __restrict__ comb_W,
                          const float* __restrict__ comb_b, float* __restrict__ x) {
    int row = blockIdx.x;
    int tid = threadIdx.x;
    const float* erow = emb + (size_t)token[0] * E;
    const float* wrow = comb_W + (size_t)row * EH;
    float acc = 0.f;
    for (int j = tid; j < EH; j += 256) {
        float c = (j < E) ? erow[j] : attn_applied[j - E];
        acc += c * wrow[j];
    }
    __shared__ float red[256];
    red[tid] = acc; __syncthreads();
    for (int s = 128; s > 0; s >>= 1) {
        if (tid < s) red[tid] += red[tid + s];
        __syncthreads();
    }
    if (tid == 0) x[row] = fmaxf(red[0] + comb_b[row], 0.f);
}

// ---------------- kernel 4: gi = x @ W_ih.T + b_ih (768 blocks, exactly balanced)
__global__ void k_gi(const float* __restrict__ x, const float* __restrict__ W_ih,
                     const float* __restrict__ b_ih, float* __restrict__ gi) {
    int lane = threadIdx.x & 63;
    int w = blockIdx.x * 4 + (threadIdx.x >> 6);    // [0, 3072)
    const float4* x4 = (const float4*)x;
    float4 xr[8];
    #pragma unroll
    for (int i = 0; i < 8; i++) xr[i] = x4[i * 64 + lane];
    int r = w * 2;                                   // rows r, r+1 of 6144
    const float4* w0 = (const float4*)(W_ih + (size_t)r * H);
    const float4* w1 = (const float4*)(W_ih + (size_t)(r + 1) * H);
    float a0 = 0.f, a1 = 0.f;
    #pragma unroll
    for (int i = 0; i < 8; i++) {
        float4 p = w0[i * 64 + lane];
        float4 q = w1[i * 64 + lane];
        a0 += xr[i].x * p.x + xr[i].y * p.y + xr[i].z * p.z + xr[i].w * p.w;
        a1 += xr[i].x * q.x + xr[i].y * q.y + xr[i].z * q.z + xr[i].w * q.w;
    }
    #pragma unroll
    for (int off = 32; off > 0; off >>= 1) {
        a0 += __shfl_xor(a0, off, 64);
        a1 += __shfl_xor(a1, off, 64);
    }
    if (lane == 0) {
        gi[r]     = a0 + b_ih[r];
        gi[r + 1] = a1 + b_ih[r + 1];
    }
}

// ---------------- kernel 5: fused GRU-elementwise + output GEMV
// 3125 blocks x 4 waves x 4 rows = exactly 50000 rows, single pass.
// Each block recomputes h_new into LDS (gi/gh are L2-hot, ~1us aggregate);
// block 0 also writes h_new to d_out.
__global__ __launch_bounds__(256) void k_out(const float* __restrict__ gi, const float* __restrict__ gh,
                                             const float* __restrict__ h0, const float* __restrict__ out_W,
                                             const float* __restrict__ out_b, float* __restrict__ logits,
                                             float* __restrict__ out_h) {
    __shared__ float hsm[H];
    int tid = threadIdx.x;
    #pragma unroll
    for (int k = 0; k < 8; ++k) {
        int idx = tid + 256 * k;
        float r = 1.f / (1.f + expf(-(gi[idx] + gh[idx])));
        float z = 1.f / (1.f + expf(-(gi[H + idx] + gh[H + idx])));
        float n = tanhf(gi[2 * H + idx] + r * gh[2 * H + idx]);
        float hv = (1.f - z) * n + z * h0[idx];
        hsm[idx] = hv;
        if (blockIdx.x == 0) out_h[idx] = hv;
    }
    __syncthreads();

    int lane = tid & 63;
    int wave = blockIdx.x * 4 + (tid >> 6);          // [0, 12500)
    const float4* h4 = (const float4*)hsm;
    float4 hreg[8];
    #pragma unroll
    for (int i = 0; i < 8; i++) hreg[i] = h4[i * 64 + lane];

    int r = wave * 4;                                 // rows r..r+3
    const float4* w0 = (const float4*)(out_W + (size_t)r * H);
    const float4* w1 = (const float4*)(out_W + (size_t)(r + 1) * H);
    const float4* w2 = (const float4*)(out_W + (size_t)(r + 2) * H);
    const float4* w3 = (const float4*)(out_W + (size_t)(r + 3) * H);
    float a0 = 0.f, a1 = 0.f, a2 = 0.f, a3 = 0.f;
    #pragma unroll
    for (int i = 0; i < 8; i++) {
        float4 hv = hreg[i];
        float4 p = w0[i * 64 + lane];
        float4 q = w1[i * 64 + lane];
        float4 s = w2[i * 64 + lane];
        float4 t = w3[i * 64 + lane];
        a0 += hv.x * p.x + hv.y * p.y + hv.z * p.z + hv.w * p.w;
        a1 += hv.x * q.x + hv.y * q.y + hv.z * q.z + hv.w * q.w;
        a2 += hv.x * s.x + hv.y * s.y + hv.z * s.z + hv.w * s.w;
        a3 += hv.x * t.x + hv.y * t.y + hv.z * t.z + hv.w * t.w;
    }
    #pragma unroll
    for (int off = 32; off > 0; off >>= 1) {
        a0 += __shfl_xor(a0, off, 64);
        a1 += __shfl_xor(a1, off, 64);
        a2 += __shfl_xor(a2, off, 64);
        a3 += __shfl_xor(a3, off, 64);
    }
    if (lane == 0) {
        logits[r]     = a0 + out_b[r];
        logits[r + 1] = a1 + out_b[r + 1];
        logits[r + 2] = a2 + out_b[r + 2];
        logits[r + 3] = a3 + out_b[r + 3];
    }
}

// ---------------- kernel 6: per-block online logsumexp partials (64 blocks)
__global__ void k_lse_part(const float* __restrict__ logits, float2* __restrict__ part) {
    int tid = threadIdx.x;
    int idx = blockIdx.x * 256 + tid;
    const int stride = 64 * 256;
    float m = -1e30f, s = 0.f;
    for (int i = idx; i < V; i += stride) {
        float xv = logits[i];
        if (xv > m) { s = s * expf(m - xv) + 1.f; m = xv; }
        else        { s += expf(xv - m); }
    }
    __shared__ float mred[256], sred[256];
    mred[tid] = m; sred[tid] = s; __syncthreads();
    for (int st = 128; st > 0; st >>= 1) {
        if (tid < st) {
            float m2 = mred[tid + st], s2 = sred[tid + st];
            float mm = fmaxf(mred[tid], m2);
            sred[tid] = sred[tid] * expf(mred[tid] - mm) + s2 * expf(m2 - mm);
            mred[tid] = mm;
        }
        __syncthreads();
    }
    if (tid == 0) part[blockIdx.x] = make_float2(mred[0], sred[0]);
}

// ---------------- kernel 7: final log_softmax write (folds 64 partials per block)
__global__ void k_logsoftmax(const float* __restrict__ logits, const float2* __restrict__ part,
                             float* __restrict__ out) {
    __shared__ float mred[64], sred[64];
    __shared__ float Csh;
    int tid = threadIdx.x;
    if (tid < 64) { float2 p = part[tid]; mred[tid] = p.x; sred[tid] = p.y; }
    __syncthreads();
    for (int st = 32; st > 0; st >>= 1) {
        if (tid < st) {
            float m2 = mred[tid + st], s2 = sred[tid + st];
            float mm = fmaxf(mred[tid], m2);
            sred[tid] = sred[tid] * expf(mred[tid] - mm) + s2 * expf(m2 - mm);
            mred[tid] = mm;
        }
        __syncthreads();
    }
    if (tid == 0) Csh = mred[0] + logf(sred[0]);
    __syncthreads();
    float C = Csh;
    int i = blockIdx.x * 256 + tid;
    if (i < V) out[i] = logits[i] - C;
}

extern "C" void kernel_launch(void* const* d_in, const int* in_sizes, int n_in,
                              void* d_out, int out_size, void* d_ws, size_t ws_size,
                              hipStream_t stream) {
    const int*   token  = (const int*)d_in[0];
    const float* hidden = (const float*)d_in[1];   // [1,1,H]
    const float* enc    = (const float*)d_in[2];   // [L,H]
    const float* emb    = (const float*)d_in[3];   // [V,E]
    const float* attn_W = (const float*)d_in[4];   // [L,EH]
    const float* attn_b = (const float*)d_in[5];   // [L]
    const float* comb_W = (const float*)d_in[6];   // [H,EH]
    const float* comb_b = (const float*)d_in[7];   // [H]
    const float* W_ih   = (const float*)d_in[8];   // [3H,H]
    const float* W_hh   = (const float*)d_in[9];   // [3H,H]
    const float* b_ih   = (const float*)d_in[10];  // [3H]
    const float* b_hh   = (const float*)d_in[11];  // [3H]
    const float* out_W  = (const float*)d_in[12];  // [V,H]
    const float* out_b  = (const float*)d_in[13];  // [V]

    float* out = (float*)d_out;
    float* ws  = (float*)d_ws;

    // ws layout (floats)
    float* scores = ws;            // 512
    float* attnap = ws + 1024;     // 2048
    float* xvec   = ws + 4096;     // 2048
    float* gi     = ws + 8192;     // 6144
    float* gh     = ws + 14336;    // 6144
    float* logits = ws + 20480;    // 50000
    float2* part  = (float2*)(ws + 70528); // 64 float2

    // d_out layout: output[50000] | h_new[2048] | attn_weights[512]
    float* out_logits = out;
    float* out_h      = out + V;
    float* out_attnw  = out + V + H;

    k_front<<<1280, 256, 0, stream>>>(token, hidden, emb, attn_W, attn_b, W_hh, b_hh,
                                      scores, attnap, gh);
    k_smax_apply<<<64, 256, 0, stream>>>(scores, enc, attnap, out_attnw);
    k_combine<<<2048, 256, 0, stream>>>(token, emb, attnap, comb_W, comb_b, xvec);
    k_gi<<<768, 256, 0, stream>>>(xvec, W_ih, b_ih, gi);
    k_out<<<3125, 256, 0, stream>>>(gi, gh, hidden, out_W, out_b, logits, out_h);
    k_lse_part<<<64, 256, 0, stream>>>(logits, part);
    k_logsoftmax<<<196, 256, 0, stream>>>(logits, part, out_logits);
}